// Round 13
// baseline (42.669 us; speedup 1.0000x reference)
//
#include <hip/hip_runtime.h>

#define BD 4
#define CD 3
#define HD 512
#define WD 512
#define NPAT 4096
#define NP (BD * NPAT)            // 16384 patches
#define PLANE (HD * WD)
#define GRID1 1024                // one block per (batch, 32x32 cell) bucket
#define SROW 51                   // slab row stride in floats (bank-spread, <=2-way)
#define TOTAL_ELEMS (4.0 * 3.0 * 4096.0 * 256.0)   // 12,582,912
#define CSTRIDE 260               // u8 count-row stride in build_order

typedef float f4 __attribute__((ext_vector_type(4), aligned(4)));

// ---- DPP cross-lane add (VALU pipe) ----
template <int CTRL>
__device__ __forceinline__ float dpp_add(float x) {
    int y = __builtin_amdgcn_update_dpp(0, __float_as_int(x), CTRL, 0xF, 0xF, true);
    return x + __int_as_float(y);
}

// Full 64-lane sum with ZERO DS ops: 4 row steps + row_bcast15 + row_bcast31,
// total lands in lane 63, broadcast back via readlane.
__device__ __forceinline__ float wave_total(float x) {
    x = dpp_add<0xB1>(x);    // quad_perm xor1
    x = dpp_add<0x4E>(x);    // quad_perm xor2
    x = dpp_add<0x124>(x);   // row_ror:4
    x = dpp_add<0x128>(x);   // row_ror:8  -> row sums in all 16 lanes
    x = dpp_add<0x142>(x);   // row_bcast15: row1 += row0, row3 += row2
    x = dpp_add<0x143>(x);   // row_bcast31: rows2,3 += (row0+row1)
    return __int_as_float(__builtin_amdgcn_readlane(__float_as_int(x), 63));
}

// ---- kernel 1: per-batch 256-key counting sort by (h>>5, w>>5) + bucket CSR ----
__global__ __launch_bounds__(256) void build_order(
    const int* __restrict__ coords, unsigned int* __restrict__ order,
    unsigned int* __restrict__ starts, unsigned int* __restrict__ counts)
{
    __shared__ unsigned char  cnt[256 * CSTRIDE];
    __shared__ unsigned short total[256];
    __shared__ unsigned int   base[256];

    const int t = threadIdx.x;
    const int b = blockIdx.x;

    {
        unsigned int* row = (unsigned int*)(cnt + t * CSTRIDE);
        #pragma unroll
        for (int k = 0; k < CSTRIDE / 4; ++k) row[k] = 0u;
    }
    __syncthreads();

    const int2* c2 = (const int2*)coords;
    unsigned int  pk[16];
    unsigned char kk[16];
    #pragma unroll
    for (int i = 0; i < 16; ++i) {
        const int p = (b << 12) + (i << 8) + t;
        const int2 hw = c2[p];
        pk[i] = ((unsigned)b << 18) | ((unsigned)hw.x << 9) | (unsigned)hw.y;
        kk[i] = (unsigned char)(((hw.x >> 5) << 4) | (hw.y >> 5));
        cnt[t * CSTRIDE + kk[i]]++;
    }
    __syncthreads();

    {
        unsigned int run = 0;
        for (int tt = 0; tt < 256; ++tt) {
            const unsigned int v = cnt[tt * CSTRIDE + t];
            cnt[tt * CSTRIDE + t] = (unsigned char)run;
            run += v;
        }
        total[t] = (unsigned short)run;
    }
    __syncthreads();

    if (t < 64) {
        const unsigned int t0 = total[4 * t],     t1 = total[4 * t + 1];
        const unsigned int t2 = total[4 * t + 2], t3 = total[4 * t + 3];
        const unsigned int lsum = t0 + t1 + t2 + t3;
        unsigned int x = lsum;
        #pragma unroll
        for (int d = 1; d < 64; d <<= 1) {
            const unsigned int v = __shfl_up(x, d, 64);
            if (t >= d) x += v;
        }
        const unsigned int excl = x - lsum;
        base[4 * t]     = excl;
        base[4 * t + 1] = excl + t0;
        base[4 * t + 2] = excl + t0 + t1;
        base[4 * t + 3] = excl + t0 + t1 + t2;
    }
    __syncthreads();

    // bucket CSR for stage1 (absolute into order[])
    starts[(b << 8) + t] = (unsigned)(b << 12) + base[t];
    counts[(b << 8) + t] = total[t];

    #pragma unroll
    for (int i = 0; i < 16; ++i) {
        const int key = kk[i];
        const unsigned int pos = base[key] + cnt[t * CSTRIDE + key];
        cnt[t * CSTRIDE + key]++;
        order[(b << 12) + pos] = pk[i];
    }
}

// ---- kernel 2: one block per bucket; stage 47x48 window in LDS, compute from LDS ----
__global__ __launch_bounds__(256) void patch_stage1(
    const float* __restrict__ fuse,
    const float* __restrict__ img1,
    const float* __restrict__ img2,
    const unsigned int* __restrict__ order,
    const unsigned int* __restrict__ starts,
    const unsigned int* __restrict__ counts,
    float* __restrict__ partials)
{
    const int tid  = threadIdx.x;
    const int lane = tid & 63;
    const int wave = tid >> 6;
    const int bid  = blockIdx.x;
    // bijective XCD-contiguous swizzle: XCD owns 128 consecutive buckets
    const int sb  = (bid & 7) * (GRID1 / 8) + (bid >> 3);
    const int b   = sb >> 8;
    const int key = sb & 255;
    const int kh  = key >> 4, kw = key & 15;

    const unsigned s = starts[sb];
    const int      n = (int)counts[sb];

    __shared__ float slab[3][47 * SROW];   // ~28.7 KB: fuse/img1/img2, one channel
    __shared__ float partsm[4];

    if (n == 0) { if (tid == 0) partials[bid] = 0.f; return; }

    const int R  = (kh == 15) ? 32 : 47;   // rows to load (clamped at image edge)
    const int C4 = (kw == 15) ? 8  : 12;   // 16B col-chunks per row (clamped)
    const float* const imgs[3] = { fuse, img1, img2 };

    float accT = 0.f;
    const float inv = 1.f / 256.f;

    for (int c = 0; c < CD; ++c) {
        // ---- stage: rows [32kh,+R) x cols [32kw,+4*C4), 3 images, streaming+aligned ----
        #pragma unroll
        for (int im = 0; im < 3; ++im) {
            const float* gp = imgs[im]
                + ((size_t)(b * CD + c) * HD + 32 * kh) * WD + 32 * kw;
            for (int i = tid; i < R * 12; i += 256) {
                const int r = i / 12;
                const int k = i - r * 12;
                if (k < C4) {
                    const f4 v = *(const f4*)(gp + (size_t)r * WD + 4 * k);
                    const int o = r * SROW + 4 * k;
                    slab[im][o]     = v.x;
                    slab[im][o + 1] = v.y;
                    slab[im][o + 2] = v.z;
                    slab[im][o + 3] = v.w;
                }
            }
        }
        __syncthreads();

        // ---- per-patch compute from LDS (4 lanes/row x 16 rows, as round 10) ----
        for (int i = wave; i < n; i += 4) {
            const unsigned o = order[s + i];
            const int w0 = (int)(o & 511)        - 32 * kw;
            const int h0 = (int)((o >> 9) & 511) - 32 * kh;
            const int base = (h0 + (lane >> 2)) * SROW + w0 + (lane & 3) * 4;

            const float a0 = slab[1][base],     a1 = slab[1][base + 1];
            const float a2 = slab[1][base + 2], a3 = slab[1][base + 3];
            const float b0 = slab[2][base],     b1 = slab[2][base + 1];
            const float b2 = slab[2][base + 2], b3 = slab[2][base + 3];
            const float f0 = slab[0][base],     f1 = slab[0][base + 1];
            const float f2 = slab[0][base + 2], f3 = slab[0][base + 3];

            const float s1 = wave_total((a0 + a1) + (a2 + a3));
            const float q1 = wave_total((a0 * a0 + a1 * a1) + (a2 * a2 + a3 * a3));
            const float s2 = wave_total((b0 + b1) + (b2 + b3));
            const float q2 = wave_total((b0 * b0 + b1 * b1) + (b2 * b2 + b3 * b3));

            const float mu1 = s1 * inv, mu2 = s2 * inv;
            const float sd1 = sqrtf(fmaxf(q1 * inv - mu1 * mu1, 0.f));
            const float sd2 = sqrtf(fmaxf(q2 * inv - mu2 * mu2, 0.f));
            const float den = sd1 + sd2 + 1e-6f;
            const float w1 = sd1 / den, w2 = sd2 / den;

            accT += fabsf(f0 - (w1 * a0 + w2 * b0))
                  + fabsf(f1 - (w1 * a1 + w2 * b1))
                  + fabsf(f2 - (w1 * a2 + w2 * b2))
                  + fabsf(f3 - (w1 * a3 + w2 * b3));
        }
        __syncthreads();
    }

    const float tot = wave_total(accT);
    if (lane == 0) partsm[wave] = tot;
    __syncthreads();
    if (tid == 0)
        partials[bid] = partsm[0] + partsm[1] + partsm[2] + partsm[3];
}

// ---- kernel 3: final reduction over 1024 partials ----
__global__ __launch_bounds__(256) void patch_stage2(
    const float* __restrict__ partials, float* __restrict__ out)
{
    float s = 0.f;
    for (int i = threadIdx.x; i < GRID1; i += 256)
        s += partials[i];

    s = wave_total(s);

    __shared__ float partsm[4];
    const int lane = threadIdx.x & 63;
    const int wave = threadIdx.x >> 6;
    if (lane == 0) partsm[wave] = s;
    __syncthreads();
    if (threadIdx.x == 0)
        out[0] = (partsm[0] + partsm[1] + partsm[2] + partsm[3]) * (float)(1.0 / TOTAL_ELEMS);
}

extern "C" void kernel_launch(void* const* d_in, const int* in_sizes, int n_in,
                              void* d_out, int out_size, void* d_ws, size_t ws_size,
                              hipStream_t stream) {
    const float* fuse   = (const float*)d_in[0];
    const float* img1   = (const float*)d_in[1];
    const float* img2   = (const float*)d_in[2];
    const int*   coords = (const int*)d_in[3];
    float* out = (float*)d_out;

    unsigned int* order    = (unsigned int*)d_ws;        // 64 KB
    unsigned int* starts   = order + NP;                 // 4 KB
    unsigned int* counts   = starts + GRID1;             // 4 KB
    float*        partials = (float*)(counts + GRID1);   // 4 KB

    build_order<<<BD, 256, 0, stream>>>(coords, order, starts, counts);
    patch_stage1<<<GRID1, 256, 0, stream>>>(fuse, img1, img2, order,
                                            starts, counts, partials);
    patch_stage2<<<1, 256, 0, stream>>>(partials, out);
}

// Round 14
// 30.130 us; speedup vs baseline: 1.4161x; 1.4161x over previous
//
#include <hip/hip_runtime.h>

#define BD 4
#define CD 3
#define HD 512
#define WD 512
#define NPAT 4096
#define NP (BD * NPAT)            // 16384 patches
#define PLANE (HD * WD)
#define PPW 2                     // patches per wave
#define PPB (PPW * 4)             // 8 patches per 256-thread block
#define NBLK (NP / PPB)           // 2048 stage1 blocks
#define TOTAL_ELEMS (4.0 * 3.0 * 4096.0 * 256.0)   // 12,582,912

typedef float f4 __attribute__((ext_vector_type(4), aligned(4)));

// ---- DPP cross-lane add (VALU pipe) ----
template <int CTRL>
__device__ __forceinline__ float dpp_add(float x) {
    int y = __builtin_amdgcn_update_dpp(0, __float_as_int(x), CTRL, 0xF, 0xF, true);
    return x + __int_as_float(y);
}

// Full 64-lane sum with ZERO DS ops (verified in round 13, absmax 0.0):
// 4 row steps + row_bcast15 + row_bcast31 -> lane 63 has total; readlane bcast.
__device__ __forceinline__ float wave_total(float x) {
    x = dpp_add<0xB1>(x);    // quad_perm xor1
    x = dpp_add<0x4E>(x);    // quad_perm xor2
    x = dpp_add<0x124>(x);   // row_ror:4
    x = dpp_add<0x128>(x);   // row_ror:8  -> all 16 lanes hold row sum
    x = dpp_add<0x142>(x);   // row_bcast15
    x = dpp_add<0x143>(x);   // row_bcast31 -> lane 63 = wave total
    return __int_as_float(__builtin_amdgcn_readlane(__float_as_int(x), 63));
}

// ---- kernel 1: per-batch counting sort by 32-row h-band (64-key, round-10) ----
__global__ __launch_bounds__(256) void build_order(
    const int* __restrict__ coords, unsigned int* __restrict__ order)
{
    __shared__ unsigned short cnt[256][18];   // padded: odd word-stride, no conflicts
    __shared__ unsigned short part[16][17];
    __shared__ unsigned int   base[16];

    const int t = threadIdx.x;
    const int b = blockIdx.x;
    const int key16 = t >> 4;
    const int sub   = t & 15;

    #pragma unroll
    for (int k = 0; k < 16; ++k) cnt[t][k] = 0;
    __syncthreads();

    const int2* c2 = (const int2*)coords;
    unsigned int pk[16];
    #pragma unroll
    for (int i = 0; i < 16; ++i) {
        const int p = (b << 12) + (i << 8) + t;
        const int2 hw = c2[p];
        pk[i] = ((unsigned)b << 18) | ((unsigned)hw.x << 9) | (unsigned)hw.y;
        cnt[t][hw.x >> 5]++;
    }
    __syncthreads();

    unsigned run = 0;
    #pragma unroll
    for (int tt = sub * 16; tt < sub * 16 + 16; ++tt) run += cnt[tt][key16];
    part[key16][sub] = (unsigned short)run;
    __syncthreads();

    if (t < 16) {
        unsigned r = 0;
        #pragma unroll
        for (int s = 0; s < 16; ++s) { unsigned v = part[t][s]; part[t][s] = (unsigned short)r; r += v; }
        base[t] = r;
    }
    __syncthreads();
    if (t == 0) {
        unsigned r = 0;
        #pragma unroll
        for (int k = 0; k < 16; ++k) { unsigned v = base[k]; base[k] = r; r += v; }
    }
    __syncthreads();

    {
        unsigned r = part[key16][sub];
        #pragma unroll
        for (int tt = sub * 16; tt < sub * 16 + 16; ++tt) {
            unsigned v = cnt[tt][key16]; cnt[tt][key16] = (unsigned short)r; r += v;
        }
    }
    __syncthreads();

    #pragma unroll
    for (int i = 0; i < 16; ++i) {
        const unsigned key = (pk[i] >> 14) & 15;
        const unsigned pos = base[key] + cnt[t][key];
        cnt[t][key]++;
        order[(b << 12) + pos] = pk[i];
    }
}

// ---- kernel 2: 2 patches/wave, all loads up front, zero-DS reductions ----
__global__ __launch_bounds__(256) void patch_stage1(
    const float* __restrict__ fuse,
    const float* __restrict__ img1,
    const float* __restrict__ img2,
    const unsigned int* __restrict__ order,
    float* __restrict__ partials)
{
    const int lane = threadIdx.x & 63;
    const int wave = threadIdx.x >> 6;
    const int bid  = blockIdx.x;
    // bijective XCD-contiguous swizzle over sorted slots (NBLK % 8 == 0)
    const int slot0 = (((bid & 7) * (NBLK / 8) + (bid >> 3)) << 3) + wave * PPW;

    const uint2 ord = *(const uint2*)(order + slot0);

    const int wA = ord.x & 511, hA = (ord.x >> 9) & 511, bA = ord.x >> 18;
    const int wB = ord.y & 511, hB = (ord.y >> 9) & 511, bB = ord.y >> 18;

    const int roff = (lane >> 2) * WD + (lane & 3) * 4;
    const size_t baseA = ((size_t)(bA * CD) * HD + hA) * WD + wA + roff;
    const size_t baseB = ((size_t)(bB * CD) * HD + hB) * WD + wB + roff;

    // Issue all 18 16B loads before any dependent compute.
    f4 vfA[3], v1A[3], v2A[3], vfB[3], v1B[3], v2B[3];
    #pragma unroll
    for (int c = 0; c < CD; ++c) {
        vfA[c] = *(const f4*)(fuse + baseA + (size_t)c * PLANE);
        v1A[c] = *(const f4*)(img1 + baseA + (size_t)c * PLANE);
        v2A[c] = *(const f4*)(img2 + baseA + (size_t)c * PLANE);
        vfB[c] = *(const f4*)(fuse + baseB + (size_t)c * PLANE);
        v1B[c] = *(const f4*)(img1 + baseB + (size_t)c * PLANE);
        v2B[c] = *(const f4*)(img2 + baseB + (size_t)c * PLANE);
    }

    float s1[2][3], q1[2][3], s2[2][3], q2[2][3];
    #pragma unroll
    for (int c = 0; c < CD; ++c) {
        s1[0][c] = v1A[c].x + v1A[c].y + v1A[c].z + v1A[c].w;
        q1[0][c] = v1A[c].x*v1A[c].x + v1A[c].y*v1A[c].y + v1A[c].z*v1A[c].z + v1A[c].w*v1A[c].w;
        s2[0][c] = v2A[c].x + v2A[c].y + v2A[c].z + v2A[c].w;
        q2[0][c] = v2A[c].x*v2A[c].x + v2A[c].y*v2A[c].y + v2A[c].z*v2A[c].z + v2A[c].w*v2A[c].w;
        s1[1][c] = v1B[c].x + v1B[c].y + v1B[c].z + v1B[c].w;
        q1[1][c] = v1B[c].x*v1B[c].x + v1B[c].y*v1B[c].y + v1B[c].z*v1B[c].z + v1B[c].w*v1B[c].w;
        s2[1][c] = v2B[c].x + v2B[c].y + v2B[c].z + v2B[c].w;
        q2[1][c] = v2B[c].x*v2B[c].x + v2B[c].y*v2B[c].y + v2B[c].z*v2B[c].z + v2B[c].w*v2B[c].w;
    }

    // 24 wave-sums: pure DPP + readlane, zero DS-pipe ops
    #pragma unroll
    for (int u = 0; u < 2; ++u) {
        #pragma unroll
        for (int c = 0; c < CD; ++c) {
            s1[u][c] = wave_total(s1[u][c]);
            q1[u][c] = wave_total(q1[u][c]);
            s2[u][c] = wave_total(s2[u][c]);
            q2[u][c] = wave_total(q2[u][c]);
        }
    }

    const float inv = 1.f / 256.f;
    float acc = 0.f;
    #pragma unroll
    for (int u = 0; u < 2; ++u) {
        #pragma unroll
        for (int c = 0; c < CD; ++c) {
            const float mu1 = s1[u][c] * inv;
            const float mu2 = s2[u][c] * inv;
            const float sd1 = sqrtf(fmaxf(q1[u][c] * inv - mu1 * mu1, 0.f));
            const float sd2 = sqrtf(fmaxf(q2[u][c] * inv - mu2 * mu2, 0.f));
            const float denom = sd1 + sd2 + 1e-6f;
            const float w1 = sd1 / denom;
            const float w2 = sd2 / denom;
            const f4 vf = u ? vfB[c] : vfA[c];
            const f4 v1 = u ? v1B[c] : v1A[c];
            const f4 v2 = u ? v2B[c] : v2A[c];
            acc += fabsf(vf.x - (w1 * v1.x + w2 * v2.x))
                 + fabsf(vf.y - (w1 * v1.y + w2 * v2.y))
                 + fabsf(vf.z - (w1 * v1.z + w2 * v2.z))
                 + fabsf(vf.w - (w1 * v1.w + w2 * v2.w));
        }
    }

    acc = wave_total(acc);

    __shared__ float partsm[4];
    if (lane == 0) partsm[wave] = acc;
    __syncthreads();
    if (threadIdx.x == 0)
        partials[bid] = partsm[0] + partsm[1] + partsm[2] + partsm[3];
}

// ---- kernel 3: final reduction over 2048 partials ----
__global__ __launch_bounds__(256) void patch_stage2(
    const float* __restrict__ partials, float* __restrict__ out)
{
    float s = 0.f;
    for (int i = threadIdx.x; i < NBLK; i += 256)
        s += partials[i];

    s = wave_total(s);

    __shared__ float partsm[4];
    const int lane = threadIdx.x & 63;
    const int wave = threadIdx.x >> 6;
    if (lane == 0) partsm[wave] = s;
    __syncthreads();
    if (threadIdx.x == 0)
        out[0] = (partsm[0] + partsm[1] + partsm[2] + partsm[3]) * (float)(1.0 / TOTAL_ELEMS);
}

extern "C" void kernel_launch(void* const* d_in, const int* in_sizes, int n_in,
                              void* d_out, int out_size, void* d_ws, size_t ws_size,
                              hipStream_t stream) {
    const float* fuse   = (const float*)d_in[0];
    const float* img1   = (const float*)d_in[1];
    const float* img2   = (const float*)d_in[2];
    const int*   coords = (const int*)d_in[3];
    float* out = (float*)d_out;

    unsigned int* order    = (unsigned int*)d_ws;            // 64 KB
    float*        partials = (float*)((char*)d_ws + NP * 4); // 8 KB

    build_order<<<BD, 256, 0, stream>>>(coords, order);
    patch_stage1<<<NBLK, 256, 0, stream>>>(fuse, img1, img2, order, partials);
    patch_stage2<<<1, 256, 0, stream>>>(partials, out);
}

// Round 15
// 29.555 us; speedup vs baseline: 1.4437x; 1.0195x over previous
//
#include <hip/hip_runtime.h>

#define BD 4
#define CD 3
#define HD 512
#define WD 512
#define NPAT 4096
#define NP (BD * NPAT)            // 16384 patches
#define PLANE (HD * WD)
#define PPW 2                     // patches per wave
#define PPB (PPW * 4)             // 8 patches per 256-thread block
#define NBLK (NP / PPB)           // 2048 stage1 blocks
#define TOTAL_ELEMS (4.0 * 3.0 * 4096.0 * 256.0)   // 12,582,912

typedef float f4 __attribute__((ext_vector_type(4), aligned(4)));

// ---- DPP cross-lane add (VALU pipe) ----
template <int CTRL>
__device__ __forceinline__ float dpp_add(float x) {
    int y = __builtin_amdgcn_update_dpp(0, __float_as_int(x), CTRL, 0xF, 0xF, true);
    return x + __int_as_float(y);
}

// Full 64-lane sum with ZERO DS ops (verified: absmax 0.0 in rounds 13/14).
__device__ __forceinline__ float wave_total(float x) {
    x = dpp_add<0xB1>(x);    // quad_perm xor1
    x = dpp_add<0x4E>(x);    // quad_perm xor2
    x = dpp_add<0x124>(x);   // row_ror:4
    x = dpp_add<0x128>(x);   // row_ror:8  -> all 16 lanes hold row sum
    x = dpp_add<0x142>(x);   // row_bcast15
    x = dpp_add<0x143>(x);   // row_bcast31 -> lane 63 = wave total
    return __int_as_float(__builtin_amdgcn_readlane(__float_as_int(x), 63));
}

// ---- kernel 1: per-batch counting sort by 32-row h-band (64-key) ----
__global__ __launch_bounds__(256) void build_order(
    const int* __restrict__ coords, unsigned int* __restrict__ order)
{
    __shared__ unsigned short cnt[256][18];   // padded: odd word-stride, no conflicts
    __shared__ unsigned short part[16][17];
    __shared__ unsigned int   base[16];

    const int t = threadIdx.x;
    const int b = blockIdx.x;
    const int key16 = t >> 4;
    const int sub   = t & 15;

    #pragma unroll
    for (int k = 0; k < 16; ++k) cnt[t][k] = 0;
    __syncthreads();

    const int2* c2 = (const int2*)coords;
    unsigned int pk[16];
    #pragma unroll
    for (int i = 0; i < 16; ++i) {
        const int p = (b << 12) + (i << 8) + t;
        const int2 hw = c2[p];
        pk[i] = ((unsigned)b << 18) | ((unsigned)hw.x << 9) | (unsigned)hw.y;
        cnt[t][hw.x >> 5]++;
    }
    __syncthreads();

    unsigned run = 0;
    #pragma unroll
    for (int tt = sub * 16; tt < sub * 16 + 16; ++tt) run += cnt[tt][key16];
    part[key16][sub] = (unsigned short)run;
    __syncthreads();

    if (t < 16) {
        unsigned r = 0;
        #pragma unroll
        for (int s = 0; s < 16; ++s) { unsigned v = part[t][s]; part[t][s] = (unsigned short)r; r += v; }
        base[t] = r;
    }
    __syncthreads();
    if (t == 0) {
        unsigned r = 0;
        #pragma unroll
        for (int k = 0; k < 16; ++k) { unsigned v = base[k]; base[k] = r; r += v; }
    }
    __syncthreads();

    {
        unsigned r = part[key16][sub];
        #pragma unroll
        for (int tt = sub * 16; tt < sub * 16 + 16; ++tt) {
            unsigned v = cnt[tt][key16]; cnt[tt][key16] = (unsigned short)r; r += v;
        }
    }
    __syncthreads();

    #pragma unroll
    for (int i = 0; i < 16; ++i) {
        const unsigned key = (pk[i] >> 14) & 15;
        const unsigned pos = base[key] + cnt[t][key];
        cnt[t][key]++;
        order[(b << 12) + pos] = pk[i];
    }
}

// ---- kernel 2: 2 patches/wave, CHANNEL-PHASED loads (3-plane L2 window) ----
__global__ __launch_bounds__(256) void patch_stage1(
    const float* __restrict__ fuse,
    const float* __restrict__ img1,
    const float* __restrict__ img2,
    const unsigned int* __restrict__ order,
    float* __restrict__ partials)
{
    const int lane = threadIdx.x & 63;
    const int wave = threadIdx.x >> 6;
    const int bid  = blockIdx.x;
    // bijective XCD-contiguous swizzle over sorted slots (NBLK % 8 == 0)
    const int slot0 = (((bid & 7) * (NBLK / 8) + (bid >> 3)) << 3) + wave * PPW;

    const uint2 ord = *(const uint2*)(order + slot0);

    const int wA = ord.x & 511, hA = (ord.x >> 9) & 511, bA = ord.x >> 18;
    const int wB = ord.y & 511, hB = (ord.y >> 9) & 511, bB = ord.y >> 18;

    const int roff = (lane >> 2) * WD + (lane & 3) * 4;
    const size_t baseA = ((size_t)(bA * CD) * HD + hA) * WD + wA + roff;
    const size_t baseB = ((size_t)(bB * CD) * HD + hB) * WD + wB + roff;

    const float inv = 1.f / 256.f;
    float acc = 0.f;

    // Channel phases kept SEQUENTIAL (unroll 1): only 3 planes live per phase,
    // so the per-XCD instantaneous L2 footprint is ~2.3 MB (< 4 MB L2) instead
    // of ~6.9 MB with all 9 planes interleaved.
    #pragma unroll 1
    for (int c = 0; c < CD; ++c) {
        const size_t oc = (size_t)c * PLANE;
        const f4 vfA = *(const f4*)(fuse + baseA + oc);
        const f4 v1A = *(const f4*)(img1 + baseA + oc);
        const f4 v2A = *(const f4*)(img2 + baseA + oc);
        const f4 vfB = *(const f4*)(fuse + baseB + oc);
        const f4 v1B = *(const f4*)(img1 + baseB + oc);
        const f4 v2B = *(const f4*)(img2 + baseB + oc);

        float s1A = (v1A.x + v1A.y) + (v1A.z + v1A.w);
        float q1A = (v1A.x*v1A.x + v1A.y*v1A.y) + (v1A.z*v1A.z + v1A.w*v1A.w);
        float s2A = (v2A.x + v2A.y) + (v2A.z + v2A.w);
        float q2A = (v2A.x*v2A.x + v2A.y*v2A.y) + (v2A.z*v2A.z + v2A.w*v2A.w);
        float s1B = (v1B.x + v1B.y) + (v1B.z + v1B.w);
        float q1B = (v1B.x*v1B.x + v1B.y*v1B.y) + (v1B.z*v1B.z + v1B.w*v1B.w);
        float s2B = (v2B.x + v2B.y) + (v2B.z + v2B.w);
        float q2B = (v2B.x*v2B.x + v2B.y*v2B.y) + (v2B.z*v2B.z + v2B.w*v2B.w);

        s1A = wave_total(s1A);  q1A = wave_total(q1A);
        s2A = wave_total(s2A);  q2A = wave_total(q2A);
        s1B = wave_total(s1B);  q1B = wave_total(q1B);
        s2B = wave_total(s2B);  q2B = wave_total(q2B);

        {
            const float mu1 = s1A * inv, mu2 = s2A * inv;
            const float sd1 = sqrtf(fmaxf(q1A * inv - mu1 * mu1, 0.f));
            const float sd2 = sqrtf(fmaxf(q2A * inv - mu2 * mu2, 0.f));
            const float den = sd1 + sd2 + 1e-6f;
            const float w1 = sd1 / den, w2 = sd2 / den;
            const f4 d = vfA - (w1 * v1A + w2 * v2A);
            acc += (fabsf(d.x) + fabsf(d.y)) + (fabsf(d.z) + fabsf(d.w));
        }
        {
            const float mu1 = s1B * inv, mu2 = s2B * inv;
            const float sd1 = sqrtf(fmaxf(q1B * inv - mu1 * mu1, 0.f));
            const float sd2 = sqrtf(fmaxf(q2B * inv - mu2 * mu2, 0.f));
            const float den = sd1 + sd2 + 1e-6f;
            const float w1 = sd1 / den, w2 = sd2 / den;
            const f4 d = vfB - (w1 * v1B + w2 * v2B);
            acc += (fabsf(d.x) + fabsf(d.y)) + (fabsf(d.z) + fabsf(d.w));
        }
    }

    acc = wave_total(acc);

    __shared__ float partsm[4];
    if (lane == 0) partsm[wave] = acc;
    __syncthreads();
    if (threadIdx.x == 0)
        partials[bid] = partsm[0] + partsm[1] + partsm[2] + partsm[3];
}

// ---- kernel 3: final reduction over 2048 partials ----
__global__ __launch_bounds__(256) void patch_stage2(
    const float* __restrict__ partials, float* __restrict__ out)
{
    float s = 0.f;
    for (int i = threadIdx.x; i < NBLK; i += 256)
        s += partials[i];

    s = wave_total(s);

    __shared__ float partsm[4];
    const int lane = threadIdx.x & 63;
    const int wave = threadIdx.x >> 6;
    if (lane == 0) partsm[wave] = s;
    __syncthreads();
    if (threadIdx.x == 0)
        out[0] = (partsm[0] + partsm[1] + partsm[2] + partsm[3]) * (float)(1.0 / TOTAL_ELEMS);
}

extern "C" void kernel_launch(void* const* d_in, const int* in_sizes, int n_in,
                              void* d_out, int out_size, void* d_ws, size_t ws_size,
                              hipStream_t stream) {
    const float* fuse   = (const float*)d_in[0];
    const float* img1   = (const float*)d_in[1];
    const float* img2   = (const float*)d_in[2];
    const int*   coords = (const int*)d_in[3];
    float* out = (float*)d_out;

    unsigned int* order    = (unsigned int*)d_ws;            // 64 KB
    float*        partials = (float*)((char*)d_ws + NP * 4); // 8 KB

    build_order<<<BD, 256, 0, stream>>>(coords, order);
    patch_stage1<<<NBLK, 256, 0, stream>>>(fuse, img1, img2, order, partials);
    patch_stage2<<<1, 256, 0, stream>>>(partials, out);
}